// Round 18
// baseline (251.913 us; speedup 1.0000x reference)
//
#include <hip/hip_runtime.h>
#include <hip/hip_bf16.h>

// Self-attention: B=4, S=4096, D=512, f32 in/out, bf16 MFMA internally.
// R18 = R17 config with ONE change: gemm_e256 adopts the R5-measured
// phase-split schedule (94.6us for E without epilogue vs 106us for the
// drain-0 loop): per K-tile, 2 k-slices x 2 m-halves, each phase
// {read frags; lgkm(0); barrier; [stage at last phase]; 16 MFMA;
// [counted vmcnt(8) at last phase]; barrier}. Stage targets the CURRENT
// buffer at the last phase -- all waves' reads of it retired at that
// phase's first barrier, and the tile-end vmcnt(8) waits only the OLDER
// 8 loads (next tile's buffer), leaving the just-issued 8 in flight ->
// never drains to 0 mid-loop (T4).
// Pipeline: wtrans W->bf16 (z=4); proj_f32 {k,v,q} f32 read + fused cvt ->
// KP/VP/QP (z=3); VWT[b]=(v_proj@Wo)^T (4-wave GEMM); E: P'=exp(qp@kp^T*s)
// + PART partial row sums (no atomics); reduce: ROWSUM=sum(PART);
// out=(P'@VWT^T)/rowsum + bo (4-wave GEMM, f32).
// Softmax = exp/rowsum (max-free: |E*scale| <~ 8 for N(0,1) scores).

typedef __attribute__((ext_vector_type(8))) short bf16x8;
typedef __attribute__((ext_vector_type(4))) float f32x4;
typedef __attribute__((ext_vector_type(8))) unsigned short u16x8;

#define DEVI static __device__ __forceinline__

DEVI unsigned short f2b(float x) {
  __hip_bfloat16 h = __float2bfloat16(x);
  return __builtin_bit_cast(unsigned short, h);
}

typedef const void __attribute__((address_space(1)))* gptr_t;
typedef void __attribute__((address_space(3)))* lptr_t;

DEVI void gload_lds16(const void* g, void* l) {
  __builtin_amdgcn_global_load_lds((gptr_t)g, (lptr_t)l, 16, 0, 0);
}

// ---- W [512,512] f32 -> WT [512,512] bf16 transpose, z selects W ---------
__global__ void wtrans4_f32(const float* __restrict__ w0,
                            const float* __restrict__ w1,
                            const float* __restrict__ w2,
                            const float* __restrict__ w3,
                            unsigned short* __restrict__ WT) {
  __shared__ unsigned short s[32][33];
  const float* W = blockIdx.z == 0 ? w0 : (blockIdx.z == 1 ? w1
                   : (blockIdx.z == 2 ? w2 : w3));
  unsigned short* dst = WT + (long)blockIdx.z * 512 * 512;
  int tx = threadIdx.x, ty = threadIdx.y;   // (32,8)
  int bx = blockIdx.x, by = blockIdx.y;
#pragma unroll
  for (int i = 0; i < 32; i += 8)
    s[ty + i][tx] = f2b(W[(by * 32 + ty + i) * 512 + bx * 32 + tx]);
  __syncthreads();
#pragma unroll
  for (int i = 0; i < 32; i += 8)
    dst[(bx * 32 + ty + i) * 512 + by * 32 + tx] = s[tx][ty + i];
}

// ---- ROWSUM[r] = sum over NSLOT slots of PART[slot][r], r < 16384 --------
__global__ __launch_bounds__(256) void reduce_partials(
    const float* __restrict__ part, float* __restrict__ rowsum, int nslot) {
  int r = blockIdx.x * 256 + threadIdx.x;
  float s = 0.f;
#pragma unroll 8
  for (int i = 0; i < nslot; ++i) s += part[(long)i * 16384 + r];
  rowsum[r] = s;
}

// ---- proj_f32: C[z] = X[z](f32) @ WT[z]^T + b[z], 128^2 4-wave engine ----
__global__ __launch_bounds__(256, 2) void proj_f32(
    const float* __restrict__ x0, const float* __restrict__ x1,
    const float* __restrict__ x2,
    const unsigned short* __restrict__ WT,
    unsigned short* __restrict__ Cout,
    const float* __restrict__ b0, const float* __restrict__ b1,
    const float* __restrict__ b2, int M) {
  const int K = 512, N = 512;
  __shared__ unsigned short As[2][128 * 64];
  __shared__ unsigned short Bs[2][128 * 64];

  const int gx = gridDim.x, gy = gridDim.y;
  const int nwg = gx * gy * gridDim.z;
  const int orig = (blockIdx.z * gy + blockIdx.y) * gx + blockIdx.x;
  const int qch = nwg >> 3;
  const int wg = (orig & 7) * qch + (orig >> 3);
  const int bx = wg % gx;
  const int tmp = wg / gx;
  const int by = tmp % gy;
  const int bz = tmp / gy;

  const float* Af = bz == 0 ? x0 : (bz == 1 ? x1 : x2);
  const unsigned short* Bb = WT + (long)bz * 512 * 512;
  const float* bias = bz == 0 ? b0 : (bz == 1 ? b1 : b2);

  const int t = threadIdx.x;
  const int lane = t & 63;
  const int wid = t >> 6;
  const int wr = wid >> 1, wc = wid & 1;
  const int lr = lane & 15, lk = lane >> 4;
  const long row0 = (long)by * 128;
  const long col0 = (long)bx * 128;
  const int r_ = t >> 3, c_ = t & 7;

  f32x4 acc[4][4] = {};
  float4 av[8];

  auto loadA = [&](int k0) {
#pragma unroll
    for (int p = 0; p < 4; ++p) {
      int r = p * 32 + r_;
      int cs = c_ ^ (r & 7);
      const float* src = Af + (row0 + r) * (long)K + k0 + cs * 8;
      av[2 * p] = *(const float4*)src;
      av[2 * p + 1] = *(const float4*)(src + 4);
    }
  };
  auto writeA = [&](int buf) {
#pragma unroll
    for (int p = 0; p < 4; ++p) {
      u16x8 o;
      o[0] = f2b(av[2 * p].x); o[1] = f2b(av[2 * p].y);
      o[2] = f2b(av[2 * p].z); o[3] = f2b(av[2 * p].w);
      o[4] = f2b(av[2 * p + 1].x); o[5] = f2b(av[2 * p + 1].y);
      o[6] = f2b(av[2 * p + 1].z); o[7] = f2b(av[2 * p + 1].w);
      *(u16x8*)((char*)As[buf] + (p * 256 + t) * 16) = o;
    }
  };
  auto stageB = [&](int buf, int k0) {
#pragma unroll
    for (int p = 0; p < 4; ++p) {
      int r = p * 32 + r_;
      int cs = c_ ^ (r & 7);
      gload_lds16(Bb + (col0 + r) * (long)K + k0 + cs * 8,
                  (char*)Bs[buf] + (p * 256 + t) * 16);
    }
  };

  const int nt = K >> 6;   // 8
  loadA(0);
  stageB(0, 0);
  writeA(0);
  asm volatile("s_waitcnt vmcnt(0)" ::: "memory");
  loadA(64);
  asm volatile("s_waitcnt lgkmcnt(0)" ::: "memory");
  int rd = 0;
  for (int tt = 0; tt < nt; ++tt) {
    if (tt + 1 < nt) {
      writeA(rd ^ 1);
      stageB(rd ^ 1, (tt + 1) << 6);
      if (tt + 2 < nt) loadA((tt + 2) << 6);
    } else {
      asm volatile("s_waitcnt vmcnt(0)" ::: "memory");
    }
    __builtin_amdgcn_sched_barrier(0);
    __builtin_amdgcn_s_barrier();
#pragma unroll
    for (int ks = 0; ks < 2; ++ks) {
      bf16x8 af[4], bfr[4];
#pragma unroll
      for (int mi = 0; mi < 4; ++mi) {
        int row = wr * 64 + mi * 16 + lr;
        int cc = (ks * 4 + lk) ^ (row & 7);
        af[mi] = *(const bf16x8*)((const char*)As[rd] + row * 128 + cc * 16);
      }
#pragma unroll
      for (int ni = 0; ni < 4; ++ni) {
        int row = wc * 64 + ni * 16 + lr;
        int cc = (ks * 4 + lk) ^ (row & 7);
        bfr[ni] = *(const bf16x8*)((const char*)Bs[rd] + row * 128 + cc * 16);
      }
#pragma unroll
      for (int mi = 0; mi < 4; ++mi)
#pragma unroll
        for (int ni = 0; ni < 4; ++ni)
          acc[mi][ni] = __builtin_amdgcn_mfma_f32_16x16x32_bf16(
              af[mi], bfr[ni], acc[mi][ni], 0, 0, 0);
    }
    asm volatile("s_waitcnt lgkmcnt(0)" ::: "memory");
    __builtin_amdgcn_s_barrier();
    rd ^= 1;
  }

  unsigned short* Cb = Cout + (long)bz * 8388608;
#pragma unroll
  for (int mi = 0; mi < 4; ++mi) {
#pragma unroll
    for (int ni = 0; ni < 4; ++ni) {
#pragma unroll
      for (int r = 0; r < 4; ++r) {
        long row = row0 + wr * 64 + mi * 16 + lk * 4 + r;
        long col = col0 + wc * 64 + ni * 16 + lr;
        Cb[row * N + col] = f2b(acc[mi][ni][r] + bias[col]);
      }
    }
  }
}

// ------------- NT GEMM: C[M,N] = A[M,K]*B[N,K]^T (128x128, 4 waves) -------
// EPI: 0 = bf16 store; 2 = f32 store, acc/rowsum[row] + bias0[col]
template <int EPI, bool HAS_BIAS>
__global__ __launch_bounds__(256, 2) void gemm_nt(
    const unsigned short* __restrict__ A,
    const unsigned short* __restrict__ B,
    void* __restrict__ Cv,
    const float* __restrict__ bias0,
    float* __restrict__ rowsum,
    int M, int N, int K, long sA, long sB, long sC) {
  __shared__ unsigned short As[2][128 * 64];
  __shared__ unsigned short Bs[2][128 * 64];

  const int gx = gridDim.x, gy = gridDim.y;
  const int nwg = gx * gy * gridDim.z;
  const int orig = (blockIdx.z * gy + blockIdx.y) * gx + blockIdx.x;
  const int qch = nwg >> 3;
  const int wg = (orig & 7) * qch + (orig >> 3);
  const int bx = wg % gx;
  const int tmp = wg / gx;
  const int by = tmp % gy;
  const int bz = tmp / gy;

  const unsigned short* Ab = A + (long)bz * sA;
  const unsigned short* Bb = B + (long)bz * sB;

  const int t = threadIdx.x;
  const int lane = t & 63;
  const int wid = t >> 6;
  const int wr = wid >> 1, wc = wid & 1;
  const int lr = lane & 15, lk = lane >> 4;
  const long row0 = (long)by * 128;
  const long col0 = (long)bx * 128;
  const int r_ = t >> 3, c_ = t & 7;

  f32x4 acc[4][4] = {};

  auto stage = [&](int buf, int k0) {
#pragma unroll
    for (int p = 0; p < 4; ++p) {
      int r = p * 32 + r_;
      int cs = c_ ^ (r & 7);
      gload_lds16(Ab + (row0 + r) * (long)K + k0 + cs * 8,
                  (char*)As[buf] + (p * 256 + t) * 16);
    }
#pragma unroll
    for (int p = 0; p < 4; ++p) {
      int r = p * 32 + r_;
      int cs = c_ ^ (r & 7);
      gload_lds16(Bb + (col0 + r) * (long)K + k0 + cs * 8,
                  (char*)Bs[buf] + (p * 256 + t) * 16);
    }
  };

  const int nt = K >> 6;
  stage(0, 0);
  int cur = 0;
  for (int tt = 0; tt < nt; ++tt) {
    if (tt + 1 < nt) {
      stage(cur ^ 1, (tt + 1) << 6);
      asm volatile("s_waitcnt vmcnt(8)" ::: "memory");
    } else {
      asm volatile("s_waitcnt vmcnt(0)" ::: "memory");
    }
    __builtin_amdgcn_s_barrier();
#pragma unroll
    for (int ks = 0; ks < 2; ++ks) {
      bf16x8 af[4], bfr[4];
#pragma unroll
      for (int mi = 0; mi < 4; ++mi) {
        int row = wr * 64 + mi * 16 + lr;
        int cc = (ks * 4 + lk) ^ (row & 7);
        af[mi] = *(const bf16x8*)((const char*)As[cur] + row * 128 + cc * 16);
      }
#pragma unroll
      for (int ni = 0; ni < 4; ++ni) {
        int row = wc * 64 + ni * 16 + lr;
        int cc = (ks * 4 + lk) ^ (row & 7);
        bfr[ni] = *(const bf16x8*)((const char*)Bs[cur] + row * 128 + cc * 16);
      }
#pragma unroll
      for (int mi = 0; mi < 4; ++mi)
#pragma unroll
        for (int ni = 0; ni < 4; ++ni)
          acc[mi][ni] = __builtin_amdgcn_mfma_f32_16x16x32_bf16(
              af[mi], bfr[ni], acc[mi][ni], 0, 0, 0);
    }
    asm volatile("s_waitcnt lgkmcnt(0)" ::: "memory");
    __builtin_amdgcn_s_barrier();
    cur ^= 1;
  }

  if constexpr (EPI == 2) {
#pragma unroll
    for (int mi = 0; mi < 4; ++mi) {
#pragma unroll
      for (int r = 0; r < 4; ++r) {
        long row = row0 + wr * 64 + mi * 16 + lk * 4 + r;
        float inv = 1.0f / rowsum[(long)bz * M + row];
#pragma unroll
        for (int ni = 0; ni < 4; ++ni) {
          long col = col0 + wc * 64 + ni * 16 + lr;
          float v = acc[mi][ni][r] * inv;
          if (HAS_BIAS) v += bias0[col];
          ((float*)Cv + bz * sC)[row * N + col] = v;
        }
      }
    }
  } else {
#pragma unroll
    for (int mi = 0; mi < 4; ++mi) {
#pragma unroll
      for (int ni = 0; ni < 4; ++ni) {
#pragma unroll
        for (int r = 0; r < 4; ++r) {
          long row = row0 + wr * 64 + mi * 16 + lk * 4 + r;
          long col = col0 + wc * 64 + ni * 16 + lr;
          float v = acc[mi][ni][r];
          if (HAS_BIAS) v += bias0[col];
          ((unsigned short*)Cv + bz * sC)[row * N + col] = f2b(v);
        }
      }
    }
  }
}

// ---- E engine: 256^2 8-wave BK=64, R5 phase-split counted-vmcnt schedule -
// P' = exp(acc*scale) bf16 + PART partial row sums (no atomics).
__global__ __launch_bounds__(512, 2) void gemm_e256(
    const unsigned short* __restrict__ A,
    const unsigned short* __restrict__ B,
    unsigned short* __restrict__ Cv,
    float* __restrict__ part,
    int M, int N, int K, long sA, long sB, long sC) {
  __shared__ unsigned short As[2][256 * 64];
  __shared__ unsigned short Bs[2][256 * 64];

  const int gx = gridDim.x, gy = gridDim.y;
  const int nwg = gx * gy * gridDim.z;
  const int orig = (blockIdx.z * gy + blockIdx.y) * gx + blockIdx.x;
  const int qch = nwg >> 3;
  const int wg = (orig & 7) * qch + (orig >> 3);
  const int bx = wg % gx;
  const int tmp = wg / gx;
  const int by = tmp % gy;
  const int bz = tmp / gy;

  const unsigned short* Ab = A + (long)bz * sA;
  const unsigned short* Bb = B + (long)bz * sB;

  const int t = threadIdx.x;
  const int lane = t & 63;
  const int wid = t >> 6;               // 8 waves: 2 (M) x 4 (N)
  const int wrow = wid >> 2, wcol = wid & 3;
  const int lr = lane & 15, lk = lane >> 4;
  const long row0 = (long)by * 256;
  const long col0 = (long)bx * 256;

  f32x4 acc[8][4] = {};

  auto stage = [&](int buf, int k0) {
#pragma unroll
    for (int p = 0; p < 4; ++p) {       // A: 256x64 bf16
      int gg = p * 512 + t;
      int r = gg >> 3, c = gg & 7;
      gload_lds16(Ab + (row0 + r) * (long)K + k0 + (c ^ (r & 7)) * 8,
                  (char*)As[buf] + gg * 16);
    }
#pragma unroll
    for (int p = 0; p < 4; ++p) {       // B: 256x64 bf16
      int gg = p * 512 + t;
      int r = gg >> 3, c = gg & 7;
      gload_lds16(Bb + (col0 + r) * (long)K + k0 + (c ^ (r & 7)) * 8,
                  (char*)Bs[buf] + gg * 16);
    }
  };

  // Process one K-tile from buffer `buf`; stage k0n into the SAME buffer
  // at the last phase (all waves' reads of it retired at that phase's
  // first barrier; this phase's MFMA operands already in registers).
  auto tile = [&](int buf, bool do_stage, int k0n) {
#pragma unroll
    for (int s = 0; s < 2; ++s) {       // k-slice (K=32 each)
      bf16x8 bfr[4];
#pragma unroll
      for (int h = 0; h < 2; ++h) {     // m-half
        bf16x8 af[4];
#pragma unroll
        for (int m = 0; m < 4; ++m) {
          int rowA = wrow * 128 + (h * 4 + m) * 16 + lr;
          af[m] = *(const bf16x8*)((const char*)As[buf] + rowA * 128 +
                                   ((s * 4 + lk) ^ (rowA & 7)) * 16);
        }
        if (h == 0) {
#pragma unroll
          for (int n = 0; n < 4; ++n) {
            int rowB = wcol * 64 + n * 16 + lr;
            bfr[n] = *(const bf16x8*)((const char*)Bs[buf] + rowB * 128 +
                                      ((s * 4 + lk) ^ (rowB & 7)) * 16);
          }
        }
        asm volatile("s_waitcnt lgkmcnt(0)" ::: "memory");
        __builtin_amdgcn_s_barrier();
        const bool last_phase = (s == 1) && (h == 1);
        if (last_phase && do_stage) stage(buf, k0n);
        __builtin_amdgcn_s_setprio(1);
#pragma unroll
        for (int m = 0; m < 4; ++m)
#pragma unroll
          for (int n = 0; n < 4; ++n)
            acc[h * 4 + m][n] = __builtin_amdgcn_mfma_f32_16x16x32_bf16(
                af[m], bfr[n], acc[h * 4 + m][n], 0, 0, 0);
        __builtin_amdgcn_s_setprio(0);
        if (last_phase) {
          if (do_stage)
            asm volatile("s_waitcnt vmcnt(8)" ::: "memory");  // counted
          else
            asm volatile("s_waitcnt vmcnt(0)" ::: "memory");  // tail drain
        }
        __builtin_amdgcn_s_barrier();
      }
    }
  };

  const int nt = K >> 6;                // 8 (even)
  stage(0, 0);
  stage(1, 64);
  asm volatile("s_waitcnt vmcnt(8)" ::: "memory");   // T0 landed; T1 flying
  __builtin_amdgcn_s_barrier();
  for (int kt = 0; kt < nt; kt += 2) {
    tile(0, kt + 2 < nt, (kt + 2) << 6);
    tile(1, kt + 3 < nt, (kt + 3) << 6);
  }

  const float kScale = 0.04419417382415922f;  // 1/sqrt(512)
  const int slot = bx * 4 + wcol;             // [0, 64)
#pragma unroll
  for (int m = 0; m < 8; ++m) {
#pragma unroll
    for (int r = 0; r < 4; ++r) {
      long row = row0 + wrow * 128 + m * 16 + lk * 4 + r;
      float s = 0.f;
#pragma unroll
      for (int n = 0; n < 4; ++n) {
        long col = col0 + wcol * 64 + n * 16 + lr;
        float e = __expf(acc[m][n][r] * kScale);
        (Cv + bz * sC)[row * N + col] = f2b(e);
        s += e;
      }
      s += __shfl_xor(s, 1); s += __shfl_xor(s, 2);
      s += __shfl_xor(s, 4); s += __shfl_xor(s, 8);
      if ((lane & 15) == 0)
        part[(long)slot * 16384 + (long)bz * M + row] = s;
    }
  }
}

extern "C" void kernel_launch(void* const* d_in, const int* in_sizes, int n_in,
                              void* d_out, int out_size, void* d_ws, size_t ws_size,
                              hipStream_t stream) {
  const float* k_in = (const float*)d_in[0];
  const float* v_in = (const float*)d_in[1];
  const float* q_in = (const float*)d_in[2];
  const float* Wk = (const float*)d_in[3];
  const float* bk = (const float*)d_in[4];
  const float* Wv = (const float*)d_in[5];
  const float* bv = (const float*)d_in[6];
  const float* Wq = (const float*)d_in[7];
  const float* bq = (const float*)d_in[8];
  const float* Wo = (const float*)d_in[9];
  const float* bo = (const float*)d_in[10];

  const int B = 4, S = 4096, D = 512;
  const long BS = (long)B * S;      // 16384
  const size_t MB = 1024 * 1024;
  if (ws_size < 226 * MB) return;   // leaves d_out poisoned -> visible failure

  // Workspace (226 MiB):
  //   0..128   P0..P3 (P' = exp(E*scale), bf16)
  //   128..176 KP, VP, QP (16 MiB each, uniform stride)
  //   176..192 VWT ([512,4096] bf16 per batch)
  //   192..200 PART (64 x 16384 f32)   200..201 ROWSUM (16384 f32)
  //   224..226 WTK,WTV,WTQ,WTO
  char* ws = (char*)d_ws;
  unsigned short* P    = (unsigned short*)(ws + 0);
  unsigned short* KP   = (unsigned short*)(ws + 128 * MB);
  unsigned short* VP   = (unsigned short*)(ws + 144 * MB);
  unsigned short* QP   = (unsigned short*)(ws + 160 * MB);
  unsigned short* VWT  = (unsigned short*)(ws + 176 * MB);
  float* PART          = (float*)(ws + 192 * MB);
  float* ROWSUM        = (float*)(ws + 200 * MB);
  unsigned short* WTK  = (unsigned short*)(ws + 224 * MB);
  unsigned short* WTO  = WTK + 3L * 512 * 512;

  wtrans4_f32<<<dim3(16, 16, 4), dim3(32, 8), 0, stream>>>(
      Wk, Wv, Wq, Wo, WTK);

  // K/V/Q projections with fused f32->bf16 (reads k/v/q f32 directly).
  proj_f32<<<dim3(D / 128, (int)(BS / 128), 3), 256, 0, stream>>>(
      k_in, v_in, q_in, WTK, KP, bk, bv, bq, (int)BS);

  // VWT[b] = (v_proj[b] @ Wo)^T == NT(A=WTO [512,512], B=VP[b] [4096,512]).
  gemm_nt<0, false><<<dim3(S / 128, D / 128, 4), 256, 0, stream>>>(
      WTO, VP, VWT, nullptr, nullptr, D, S, D,
      0, (long)S * D, (long)S * D);

  // P'[b] = exp(qp[b] @ kp[b]^T * scale) + PART partial sums (256^2 engine).
  gemm_e256<<<dim3(S / 256, S / 256, 4), 512, 0, stream>>>(
      QP, KP, P, PART, S, S, D,
      (long)S * D, (long)S * D, (long)S * S);

  // ROWSUM = sum over 64 slots of PART.
  reduce_partials<<<64, 256, 0, stream>>>(PART, ROWSUM, 64);

  // out[b] = (P'[b] @ VWT[b]^T)/rowsum + bo (f32 straight to d_out), z=4.
  gemm_nt<2, true><<<dim3(D / 128, S / 128, 4), 256, 0, stream>>>(
      P, VWT, d_out, bo, ROWSUM, S, D, S,
      (long)S * S, (long)S * D, (long)S * D);
}

// Round 19
// 249.319 us; speedup vs baseline: 1.0104x; 1.0104x over previous
//
#include <hip/hip_runtime.h>
#include <hip/hip_bf16.h>

// Self-attention: B=4, S=4096, D=512, f32 in/out, bf16 MFMA internally.
// R19 = consolidation on the best-measured configuration (R17, 249.5us):
// revert R18's E phase-split (108.8us) to the drain-0 256^2 loop (106.1us).
// E has been probed on every axis: tile (BN=128 thrash 145; 256^2 best),
// occupancy (BK=32 2-blk/CU: 121, TLP falsified), conflicts (0), schedule
// (drain-0 106 / counted-split 108 / 1-barrier 106), fusion (290+, LDS-
// starved at D_out=512). K=512 gives only 8 tiles to amortize pipeline
// fill; PV runs at the documented m97-structure ceiling (881 TF).
// Pipeline: wtrans W->bf16 (z=4); proj_f32 {k,v,q} f32 read + fused cvt ->
// KP/VP/QP (z=3); VWT[b]=(v_proj@Wo)^T (4-wave GEMM); E: P'=exp(qp@kp^T*s)
// via 256^2/BK=64 8-wave engine + PART partial row sums (no atomics);
// reduce: ROWSUM=sum(PART); out=(P'@VWT^T)/rowsum + bo (4-wave GEMM, f32).
// Softmax = exp/rowsum (max-free: |E*scale| <~ 8 for N(0,1) scores).

typedef __attribute__((ext_vector_type(8))) short bf16x8;
typedef __attribute__((ext_vector_type(4))) float f32x4;
typedef __attribute__((ext_vector_type(8))) unsigned short u16x8;

#define DEVI static __device__ __forceinline__

DEVI unsigned short f2b(float x) {
  __hip_bfloat16 h = __float2bfloat16(x);
  return __builtin_bit_cast(unsigned short, h);
}

typedef const void __attribute__((address_space(1)))* gptr_t;
typedef void __attribute__((address_space(3)))* lptr_t;

DEVI void gload_lds16(const void* g, void* l) {
  __builtin_amdgcn_global_load_lds((gptr_t)g, (lptr_t)l, 16, 0, 0);
}

// ---- W [512,512] f32 -> WT [512,512] bf16 transpose, z selects W ---------
__global__ void wtrans4_f32(const float* __restrict__ w0,
                            const float* __restrict__ w1,
                            const float* __restrict__ w2,
                            const float* __restrict__ w3,
                            unsigned short* __restrict__ WT) {
  __shared__ unsigned short s[32][33];
  const float* W = blockIdx.z == 0 ? w0 : (blockIdx.z == 1 ? w1
                   : (blockIdx.z == 2 ? w2 : w3));
  unsigned short* dst = WT + (long)blockIdx.z * 512 * 512;
  int tx = threadIdx.x, ty = threadIdx.y;   // (32,8)
  int bx = blockIdx.x, by = blockIdx.y;
#pragma unroll
  for (int i = 0; i < 32; i += 8)
    s[ty + i][tx] = f2b(W[(by * 32 + ty + i) * 512 + bx * 32 + tx]);
  __syncthreads();
#pragma unroll
  for (int i = 0; i < 32; i += 8)
    dst[(bx * 32 + ty + i) * 512 + by * 32 + tx] = s[tx][ty + i];
}

// ---- ROWSUM[r] = sum over NSLOT slots of PART[slot][r], r < 16384 --------
__global__ __launch_bounds__(256) void reduce_partials(
    const float* __restrict__ part, float* __restrict__ rowsum, int nslot) {
  int r = blockIdx.x * 256 + threadIdx.x;
  float s = 0.f;
#pragma unroll 8
  for (int i = 0; i < nslot; ++i) s += part[(long)i * 16384 + r];
  rowsum[r] = s;
}

// ---- proj_f32: C[z] = X[z](f32) @ WT[z]^T + b[z], 128^2 4-wave engine ----
__global__ __launch_bounds__(256, 2) void proj_f32(
    const float* __restrict__ x0, const float* __restrict__ x1,
    const float* __restrict__ x2,
    const unsigned short* __restrict__ WT,
    unsigned short* __restrict__ Cout,
    const float* __restrict__ b0, const float* __restrict__ b1,
    const float* __restrict__ b2, int M) {
  const int K = 512, N = 512;
  __shared__ unsigned short As[2][128 * 64];
  __shared__ unsigned short Bs[2][128 * 64];

  const int gx = gridDim.x, gy = gridDim.y;
  const int nwg = gx * gy * gridDim.z;
  const int orig = (blockIdx.z * gy + blockIdx.y) * gx + blockIdx.x;
  const int qch = nwg >> 3;
  const int wg = (orig & 7) * qch + (orig >> 3);
  const int bx = wg % gx;
  const int tmp = wg / gx;
  const int by = tmp % gy;
  const int bz = tmp / gy;

  const float* Af = bz == 0 ? x0 : (bz == 1 ? x1 : x2);
  const unsigned short* Bb = WT + (long)bz * 512 * 512;
  const float* bias = bz == 0 ? b0 : (bz == 1 ? b1 : b2);

  const int t = threadIdx.x;
  const int lane = t & 63;
  const int wid = t >> 6;
  const int wr = wid >> 1, wc = wid & 1;
  const int lr = lane & 15, lk = lane >> 4;
  const long row0 = (long)by * 128;
  const long col0 = (long)bx * 128;
  const int r_ = t >> 3, c_ = t & 7;

  f32x4 acc[4][4] = {};
  float4 av[8];

  auto loadA = [&](int k0) {
#pragma unroll
    for (int p = 0; p < 4; ++p) {
      int r = p * 32 + r_;
      int cs = c_ ^ (r & 7);
      const float* src = Af + (row0 + r) * (long)K + k0 + cs * 8;
      av[2 * p] = *(const float4*)src;
      av[2 * p + 1] = *(const float4*)(src + 4);
    }
  };
  auto writeA = [&](int buf) {
#pragma unroll
    for (int p = 0; p < 4; ++p) {
      u16x8 o;
      o[0] = f2b(av[2 * p].x); o[1] = f2b(av[2 * p].y);
      o[2] = f2b(av[2 * p].z); o[3] = f2b(av[2 * p].w);
      o[4] = f2b(av[2 * p + 1].x); o[5] = f2b(av[2 * p + 1].y);
      o[6] = f2b(av[2 * p + 1].z); o[7] = f2b(av[2 * p + 1].w);
      *(u16x8*)((char*)As[buf] + (p * 256 + t) * 16) = o;
    }
  };
  auto stageB = [&](int buf, int k0) {
#pragma unroll
    for (int p = 0; p < 4; ++p) {
      int r = p * 32 + r_;
      int cs = c_ ^ (r & 7);
      gload_lds16(Bb + (col0 + r) * (long)K + k0 + cs * 8,
                  (char*)Bs[buf] + (p * 256 + t) * 16);
    }
  };

  const int nt = K >> 6;   // 8
  loadA(0);
  stageB(0, 0);
  writeA(0);
  asm volatile("s_waitcnt vmcnt(0)" ::: "memory");
  loadA(64);
  asm volatile("s_waitcnt lgkmcnt(0)" ::: "memory");
  int rd = 0;
  for (int tt = 0; tt < nt; ++tt) {
    if (tt + 1 < nt) {
      writeA(rd ^ 1);
      stageB(rd ^ 1, (tt + 1) << 6);
      if (tt + 2 < nt) loadA((tt + 2) << 6);
    } else {
      asm volatile("s_waitcnt vmcnt(0)" ::: "memory");
    }
    __builtin_amdgcn_sched_barrier(0);
    __builtin_amdgcn_s_barrier();
#pragma unroll
    for (int ks = 0; ks < 2; ++ks) {
      bf16x8 af[4], bfr[4];
#pragma unroll
      for (int mi = 0; mi < 4; ++mi) {
        int row = wr * 64 + mi * 16 + lr;
        int cc = (ks * 4 + lk) ^ (row & 7);
        af[mi] = *(const bf16x8*)((const char*)As[rd] + row * 128 + cc * 16);
      }
#pragma unroll
      for (int ni = 0; ni < 4; ++ni) {
        int row = wc * 64 + ni * 16 + lr;
        int cc = (ks * 4 + lk) ^ (row & 7);
        bfr[ni] = *(const bf16x8*)((const char*)Bs[rd] + row * 128 + cc * 16);
      }
#pragma unroll
      for (int mi = 0; mi < 4; ++mi)
#pragma unroll
        for (int ni = 0; ni < 4; ++ni)
          acc[mi][ni] = __builtin_amdgcn_mfma_f32_16x16x32_bf16(
              af[mi], bfr[ni], acc[mi][ni], 0, 0, 0);
    }
    asm volatile("s_waitcnt lgkmcnt(0)" ::: "memory");
    __builtin_amdgcn_s_barrier();
    rd ^= 1;
  }

  unsigned short* Cb = Cout + (long)bz * 8388608;
#pragma unroll
  for (int mi = 0; mi < 4; ++mi) {
#pragma unroll
    for (int ni = 0; ni < 4; ++ni) {
#pragma unroll
      for (int r = 0; r < 4; ++r) {
        long row = row0 + wr * 64 + mi * 16 + lk * 4 + r;
        long col = col0 + wc * 64 + ni * 16 + lr;
        Cb[row * N + col] = f2b(acc[mi][ni][r] + bias[col]);
      }
    }
  }
}

// ------------- NT GEMM: C[M,N] = A[M,K]*B[N,K]^T (128x128, 4 waves) -------
// EPI: 0 = bf16 store; 2 = f32 store, acc/rowsum[row] + bias0[col]
template <int EPI, bool HAS_BIAS>
__global__ __launch_bounds__(256, 2) void gemm_nt(
    const unsigned short* __restrict__ A,
    const unsigned short* __restrict__ B,
    void* __restrict__ Cv,
    const float* __restrict__ bias0,
    float* __restrict__ rowsum,
    int M, int N, int K, long sA, long sB, long sC) {
  __shared__ unsigned short As[2][128 * 64];
  __shared__ unsigned short Bs[2][128 * 64];

  const int gx = gridDim.x, gy = gridDim.y;
  const int nwg = gx * gy * gridDim.z;
  const int orig = (blockIdx.z * gy + blockIdx.y) * gx + blockIdx.x;
  const int qch = nwg >> 3;
  const int wg = (orig & 7) * qch + (orig >> 3);
  const int bx = wg % gx;
  const int tmp = wg / gx;
  const int by = tmp % gy;
  const int bz = tmp / gy;

  const unsigned short* Ab = A + (long)bz * sA;
  const unsigned short* Bb = B + (long)bz * sB;

  const int t = threadIdx.x;
  const int lane = t & 63;
  const int wid = t >> 6;
  const int wr = wid >> 1, wc = wid & 1;
  const int lr = lane & 15, lk = lane >> 4;
  const long row0 = (long)by * 128;
  const long col0 = (long)bx * 128;
  const int r_ = t >> 3, c_ = t & 7;

  f32x4 acc[4][4] = {};

  auto stage = [&](int buf, int k0) {
#pragma unroll
    for (int p = 0; p < 4; ++p) {
      int r = p * 32 + r_;
      int cs = c_ ^ (r & 7);
      gload_lds16(Ab + (row0 + r) * (long)K + k0 + cs * 8,
                  (char*)As[buf] + (p * 256 + t) * 16);
    }
#pragma unroll
    for (int p = 0; p < 4; ++p) {
      int r = p * 32 + r_;
      int cs = c_ ^ (r & 7);
      gload_lds16(Bb + (col0 + r) * (long)K + k0 + cs * 8,
                  (char*)Bs[buf] + (p * 256 + t) * 16);
    }
  };

  const int nt = K >> 6;
  stage(0, 0);
  int cur = 0;
  for (int tt = 0; tt < nt; ++tt) {
    if (tt + 1 < nt) {
      stage(cur ^ 1, (tt + 1) << 6);
      asm volatile("s_waitcnt vmcnt(8)" ::: "memory");
    } else {
      asm volatile("s_waitcnt vmcnt(0)" ::: "memory");
    }
    __builtin_amdgcn_s_barrier();
#pragma unroll
    for (int ks = 0; ks < 2; ++ks) {
      bf16x8 af[4], bfr[4];
#pragma unroll
      for (int mi = 0; mi < 4; ++mi) {
        int row = wr * 64 + mi * 16 + lr;
        int cc = (ks * 4 + lk) ^ (row & 7);
        af[mi] = *(const bf16x8*)((const char*)As[cur] + row * 128 + cc * 16);
      }
#pragma unroll
      for (int ni = 0; ni < 4; ++ni) {
        int row = wc * 64 + ni * 16 + lr;
        int cc = (ks * 4 + lk) ^ (row & 7);
        bfr[ni] = *(const bf16x8*)((const char*)Bs[cur] + row * 128 + cc * 16);
      }
#pragma unroll
      for (int mi = 0; mi < 4; ++mi)
#pragma unroll
        for (int ni = 0; ni < 4; ++ni)
          acc[mi][ni] = __builtin_amdgcn_mfma_f32_16x16x32_bf16(
              af[mi], bfr[ni], acc[mi][ni], 0, 0, 0);
    }
    asm volatile("s_waitcnt lgkmcnt(0)" ::: "memory");
    __builtin_amdgcn_s_barrier();
    cur ^= 1;
  }

  if constexpr (EPI == 2) {
#pragma unroll
    for (int mi = 0; mi < 4; ++mi) {
#pragma unroll
      for (int r = 0; r < 4; ++r) {
        long row = row0 + wr * 64 + mi * 16 + lk * 4 + r;
        float inv = 1.0f / rowsum[(long)bz * M + row];
#pragma unroll
        for (int ni = 0; ni < 4; ++ni) {
          long col = col0 + wc * 64 + ni * 16 + lr;
          float v = acc[mi][ni][r] * inv;
          if (HAS_BIAS) v += bias0[col];
          ((float*)Cv + bz * sC)[row * N + col] = v;
        }
      }
    }
  } else {
#pragma unroll
    for (int mi = 0; mi < 4; ++mi) {
#pragma unroll
      for (int ni = 0; ni < 4; ++ni) {
#pragma unroll
        for (int r = 0; r < 4; ++r) {
          long row = row0 + wr * 64 + mi * 16 + lk * 4 + r;
          long col = col0 + wc * 64 + ni * 16 + lr;
          float v = acc[mi][ni][r];
          if (HAS_BIAS) v += bias0[col];
          ((unsigned short*)Cv + bz * sC)[row * N + col] = f2b(v);
        }
      }
    }
  }
}

// ---- E engine: 256^2 8-wave BK=64 drain-0 loop (R12/R17-measured 106us) -
// P' = exp(acc*scale) bf16 + PART partial row sums (no atomics).
__global__ __launch_bounds__(512, 2) void gemm_e256(
    const unsigned short* __restrict__ A,
    const unsigned short* __restrict__ B,
    unsigned short* __restrict__ Cv,
    float* __restrict__ part,
    int M, int N, int K, long sA, long sB, long sC) {
  __shared__ unsigned short As[2][256 * 64];
  __shared__ unsigned short Bs[2][256 * 64];

  const int gx = gridDim.x, gy = gridDim.y;
  const int nwg = gx * gy * gridDim.z;
  const int orig = (blockIdx.z * gy + blockIdx.y) * gx + blockIdx.x;
  const int qch = nwg >> 3;
  const int wg = (orig & 7) * qch + (orig >> 3);
  const int bx = wg % gx;
  const int tmp = wg / gx;
  const int by = tmp % gy;
  const int bz = tmp / gy;

  const unsigned short* Ab = A + (long)bz * sA;
  const unsigned short* Bb = B + (long)bz * sB;

  const int t = threadIdx.x;
  const int lane = t & 63;
  const int wid = t >> 6;               // 8 waves: 2 (M) x 4 (N)
  const int wrow = wid >> 2, wcol = wid & 3;
  const int lr = lane & 15, lk = lane >> 4;
  const long row0 = (long)by * 256;
  const long col0 = (long)bx * 256;

  f32x4 acc[8][4] = {};

  auto stage = [&](int buf, int k0) {
#pragma unroll
    for (int p = 0; p < 4; ++p) {       // A: 256x64 bf16
      int gg = p * 512 + t;
      int r = gg >> 3, c = gg & 7;
      gload_lds16(Ab + (row0 + r) * (long)K + k0 + (c ^ (r & 7)) * 8,
                  (char*)As[buf] + gg * 16);
    }
#pragma unroll
    for (int p = 0; p < 4; ++p) {       // B: 256x64 bf16
      int gg = p * 512 + t;
      int r = gg >> 3, c = gg & 7;
      gload_lds16(Bb + (col0 + r) * (long)K + k0 + (c ^ (r & 7)) * 8,
                  (char*)Bs[buf] + gg * 16);
    }
  };

  const int nt = K >> 6;
  stage(0, 0);
  asm volatile("s_waitcnt vmcnt(0)" ::: "memory");
  __builtin_amdgcn_s_barrier();

  int cur = 0;
  for (int tt = 0; tt < nt; ++tt) {
    if (tt + 1 < nt) stage(cur ^ 1, (tt + 1) << 6);
    __builtin_amdgcn_s_setprio(1);
#pragma unroll
    for (int s = 0; s < 2; ++s) {
      bf16x8 bfr[4];
#pragma unroll
      for (int n = 0; n < 4; ++n) {
        int rowB = wcol * 64 + n * 16 + lr;
        bfr[n] = *(const bf16x8*)((const char*)Bs[cur] + rowB * 128 +
                                  ((s * 4 + lk) ^ (rowB & 7)) * 16);
      }
#pragma unroll
      for (int h = 0; h < 2; ++h) {
        bf16x8 af[4];
#pragma unroll
        for (int m = 0; m < 4; ++m) {
          int rowA = wrow * 128 + (h * 4 + m) * 16 + lr;
          af[m] = *(const bf16x8*)((const char*)As[cur] + rowA * 128 +
                                   ((s * 4 + lk) ^ (rowA & 7)) * 16);
        }
#pragma unroll
        for (int m = 0; m < 4; ++m)
#pragma unroll
          for (int n = 0; n < 4; ++n)
            acc[h * 4 + m][n] = __builtin_amdgcn_mfma_f32_16x16x32_bf16(
                af[m], bfr[n], acc[h * 4 + m][n], 0, 0, 0);
      }
    }
    __builtin_amdgcn_s_setprio(0);
    asm volatile("s_waitcnt vmcnt(0)" ::: "memory");
    __builtin_amdgcn_sched_barrier(0);
    __builtin_amdgcn_s_barrier();
    cur ^= 1;
  }

  const float kScale = 0.04419417382415922f;  // 1/sqrt(512)
  const int slot = bx * 4 + wcol;             // [0, 64)
#pragma unroll
  for (int m = 0; m < 8; ++m) {
#pragma unroll
    for (int r = 0; r < 4; ++r) {
      long row = row0 + wrow * 128 + m * 16 + lk * 4 + r;
      float s = 0.f;
#pragma unroll
      for (int n = 0; n < 4; ++n) {
        long col = col0 + wcol * 64 + n * 16 + lr;
        float e = __expf(acc[m][n][r] * kScale);
        (Cv + bz * sC)[row * N + col] = f2b(e);
        s += e;
      }
      s += __shfl_xor(s, 1); s += __shfl_xor(s, 2);
      s += __shfl_xor(s, 4); s += __shfl_xor(s, 8);
      if ((lane & 15) == 0)
        part[(long)slot * 16384 + (long)bz * M + row] = s;
    }
  }
}

extern "C" void kernel_launch(void* const* d_in, const int* in_sizes, int n_in,
                              void* d_out, int out_size, void* d_ws, size_t ws_size,
                              hipStream_t stream) {
  const float* k_in = (const float*)d_in[0];
  const float* v_in = (const float*)d_in[1];
  const float* q_in = (const float*)d_in[2];
  const float* Wk = (const float*)d_in[3];
  const float* bk = (const float*)d_in[4];
  const float* Wv = (const float*)d_in[5];
  const float* bv = (const float*)d_in[6];
  const float* Wq = (const float*)d_in[7];
  const float* bq = (const float*)d_in[8];
  const float* Wo = (const float*)d_in[9];
  const float* bo = (const float*)d_in[10];

  const int B = 4, S = 4096, D = 512;
  const long BS = (long)B * S;      // 16384
  const size_t MB = 1024 * 1024;
  if (ws_size < 226 * MB) return;   // leaves d_out poisoned -> visible failure

  // Workspace (226 MiB):
  //   0..128   P0..P3 (P' = exp(E*scale), bf16)
  //   128..176 KP, VP, QP (16 MiB each, uniform stride)
  //   176..192 VWT ([512,4096] bf16 per batch)
  //   192..200 PART (64 x 16384 f32)   200..201 ROWSUM (16384 f32)
  //   224..226 WTK,WTV,WTQ,WTO
  char* ws = (char*)d_ws;
  unsigned short* P    = (unsigned short*)(ws + 0);
  unsigned short* KP   = (unsigned short*)(ws + 128 * MB);
  unsigned short* VP   = (unsigned short*)(ws + 144 * MB);
  unsigned short* QP   = (unsigned short*)(ws + 160 * MB);
  unsigned short* VWT  = (unsigned short*)(ws + 176 * MB);
  float* PART          = (float*)(ws + 192 * MB);
  float* ROWSUM        = (float*)(ws + 200 * MB);
  unsigned short* WTK  = (unsigned short*)(ws + 224 * MB);
  unsigned short* WTO  = WTK + 3L * 512 * 512;

  wtrans4_f32<<<dim3(16, 16, 4), dim3(32, 8), 0, stream>>>(
      Wk, Wv, Wq, Wo, WTK);

  // K/V/Q projections with fused f32->bf16 (reads k/v/q f32 directly).
  proj_f32<<<dim3(D / 128, (int)(BS / 128), 3), 256, 0, stream>>>(
      k_in, v_in, q_in, WTK, KP, bk, bv, bq, (int)BS);

  // VWT[b] = (v_proj[b] @ Wo)^T == NT(A=WTO [512,512], B=VP[b] [4096,512]).
  gemm_nt<0, false><<<dim3(S / 128, D / 128, 4), 256, 0, stream>>>(
      WTO, VP, VWT, nullptr, nullptr, D, S, D,
      0, (long)S * D, (long)S * D);

  // P'[b] = exp(qp[b] @ kp[b]^T * scale) + PART partial sums (256^2 engine).
  gemm_e256<<<dim3(S / 256, S / 256, 4), 512, 0, stream>>>(
      QP, KP, P, PART, S, S, D,
      (long)S * D, (long)S * D, (long)S * S);

  // ROWSUM = sum over 64 slots of PART.
  reduce_partials<<<64, 256, 0, stream>>>(PART, ROWSUM, 64);

  // out[b] = (P'[b] @ VWT[b]^T)/rowsum + bo (f32 straight to d_out), z=4.
  gemm_nt<2, true><<<dim3(D / 128, S / 128, 4), 256, 0, stream>>>(
      P, VWT, d_out, bo, ROWSUM, S, D, S,
      (long)S * S, (long)S * D, (long)S * D);
}